// Round 14
// baseline (132.876 us; speedup 1.0000x reference)
//
#include <hip/hip_runtime.h>
#include <cfloat>
#include <cstdint>

#define GBM 64
#define GBN 64
#define GBK 64
#define GPAD 68     // 68*4=272B rows: 16B-aligned for b128 frags

#define G_    169
#define D_    1024
#define H_    512
#define NW    8     // waves per feat_final block
#define ROWG  8     // rows per staged group
#define NGRP  16    // groups per wave (128 rows)
#define GRPF  1352  // ROWG*G_ floats per group
#define NV    338   // GRPF/4 float4 per group
#define NBUF  3
#define SPL   8     // split-K slices

typedef unsigned int u32;

__device__ __forceinline__ void gload_lds16(const float* g, float* l) {
    __builtin_amdgcn_global_load_lds(
        (const __attribute__((address_space(1))) u32*)g,
        (__attribute__((address_space(3))) u32*)l, 16, 0, 0);
}

// stage one 8x169 group: 6 gload_lds16 per wave (j=5 masked; still 6 vmcnt)
__device__ __forceinline__ void stage_group(const float* gsrc, float* ldsbase, int lane) {
    #pragma unroll
    for (int j = 0; j < 6; j++) {
        int idx = j * 64 + lane;
        if (idx < NV)
            gload_lds16(gsrc + 4 * idx, ldsbase + j * 256);
    }
}

// ---- split-K GEMM: py[s][M][N] partial of A[M,K] @ B[K,N], one 64^3 tile/block
__global__ __launch_bounds__(256) void gemm_splitk(
    const float* __restrict__ A, const float* __restrict__ B,
    float* __restrict__ Cpart, int M, int N, int K)
{
    __shared__ __align__(16) float Asm[GBK][GPAD];
    __shared__ __align__(16) float Bsm[GBK][GPAD];
    int t  = threadIdx.x;
    int m0 = blockIdx.y * GBM, n0 = blockIdx.x * GBN;
    int ks = blockIdx.z * GBK;

    #pragma unroll
    for (int i = 0; i < 4; i++) {
        int v = t + 256 * i;
        int m = v >> 4, k4 = (v & 15) * 4;
        float4 x = *(const float4*)&A[(size_t)(m0 + m) * K + ks + k4];
        Asm[k4 + 0][m] = x.x; Asm[k4 + 1][m] = x.y;
        Asm[k4 + 2][m] = x.z; Asm[k4 + 3][m] = x.w;
    }
    #pragma unroll
    for (int i = 0; i < 4; i++) {
        int v = t + 256 * i;
        int r = v >> 4, c4 = (v & 15) * 4;
        *(float4*)&Bsm[r][c4] = *(const float4*)&B[(size_t)(ks + r) * N + n0 + c4];
    }
    __syncthreads();

    int r4 = (t >> 4) * 4, c4 = (t & 15) * 4;
    float acc[4][4] = {{0.f}};
    #pragma unroll
    for (int kk = 0; kk < GBK; kk++) {
        float4 a = *(const float4*)&Asm[kk][r4];
        float4 b = *(const float4*)&Bsm[kk][c4];
        float av[4] = {a.x, a.y, a.z, a.w};
        float bv[4] = {b.x, b.y, b.z, b.w};
        #pragma unroll
        for (int i = 0; i < 4; i++)
            #pragma unroll
            for (int j = 0; j < 4; j++) acc[i][j] += av[i] * bv[j];
    }
    float* Cp = Cpart + (size_t)blockIdx.z * M * N;
    #pragma unroll
    for (int i = 0; i < 4; i++) {
        float4 v = {acc[i][0], acc[i][1], acc[i][2], acc[i][3]};
        *(float4*)&Cp[(size_t)(m0 + r4 + i) * N + n0 + c4] = v;
    }
}

// ---- feat_final: y from py; z per-wave inline with W_vs double-buffered in
// regs so the DMA queue keeps 2 feat groups in flight (vmcnt(28) steady). ----
__global__ __launch_bounds__(512, 2) void feat_final(
    const float* __restrict__ feat, const float* __restrict__ py,
    const float* __restrict__ W_vs,
    const float* __restrict__ boxes, const float* __restrict__ masks,
    const float* __restrict__ b_ts, const float* __restrict__ b_vs,
    const int* __restrict__ kptr,
    float* __restrict__ out_box, float* __restrict__ out_mask,
    float* __restrict__ out_max,
    int bs, int AN, int CH, int CM)
{
    __shared__ __align__(16) float buf[NW][NBUF][GRPF];   // ~130 KB
    __shared__ __align__(16) float ys[H_];
    __shared__ float accw[NW * 176];
    __shared__ float simall[176];
    __shared__ float ms[176];
    __shared__ int   selg[176];
    __shared__ float simv[176];
    __shared__ float redw[NW];
    __shared__ float bbs;
    __shared__ int   selp[2];

    const int b = blockIdx.x;
    const int t = threadIdx.x;
    const int w = t >> 6, lane = t & 63;

    // ---- y = sum_s py[s][b] + b_ts ----
    {
        float yv = b_ts[t];
        #pragma unroll
        for (int s = 0; s < SPL; s++) yv += py[((size_t)s * bs + b) * H_ + t];
        ys[t] = yv;
    }
    __syncthreads();

    const int ylo  = (lane & 7) * 4;      // col base within W row / y
    const int wrow = lane >> 3;           // row within 8-row chunk
    const float* gsrc  = feat + ((size_t)b * D_ + (size_t)w * 128) * G_;
    const float* Wbase = W_vs + ((size_t)(w * 128 + wrow)) * H_ + ylo;

    float4 wr[2][16];
    // prologue: W(0) FIRST, then stages (queue: [W0][g0][g1])
    #pragma unroll
    for (int j = 0; j < 16; j++)
        wr[0][j] = *(const float4*)&Wbase[j * 32];
    stage_group(gsrc,        buf[w][0], lane);
    stage_group(gsrc + GRPF, buf[w][1], lane);

    float acc0 = 0.f, acc1 = 0.f, acc2 = 0.f;
    const bool g2 = lane < (G_ - 128);    // 41 lanes
    #pragma unroll
    for (int gi = 0; gi < NGRP; gi++) {
        if (gi + 1 < NGRP) {              // W(gi+1) into other wr buffer
            const float* Wp = Wbase + (size_t)(gi + 1) * 8 * H_;
            #pragma unroll
            for (int j = 0; j < 16; j++)
                wr[(gi + 1) & 1][j] = *(const float4*)&Wp[j * 32];
        }
        if (gi + 2 < NGRP)
            stage_group(gsrc + (size_t)(gi + 2) * GRPF, buf[w][(gi + 2) % NBUF], lane);
        // retire g(gi)+W(gi); keep g(i+1), W(i+1), g(i+2) in flight
        if (gi + 3 <= NGRP)       // gi <= 13
            asm volatile("s_waitcnt vmcnt(28)" ::: "memory");
        else if (gi + 2 == NGRP)  // gi == 14
            asm volatile("s_waitcnt vmcnt(22)" ::: "memory");
        else                      // gi == 15
            asm volatile("s_waitcnt vmcnt(0)" ::: "memory");
        __builtin_amdgcn_sched_barrier(0);

        // z for this 8-row chunk from wr[gi&1] . y(LDS broadcast)
        float zpart = 0.f;
        #pragma unroll
        for (int j = 0; j < 16; j++) {
            float4 yv = *(const float4*)&ys[ylo + j * 32];
            float4 wv = wr[gi & 1][j];
            zpart += wv.x * yv.x + wv.y * yv.y + wv.z * yv.z + wv.w * yv.w;
        }
        zpart += __shfl_xor(zpart, 1);
        zpart += __shfl_xor(zpart, 2);
        zpart += __shfl_xor(zpart, 4);    // 8-lane groups hold z[row]

        const float* bp = buf[w][gi % NBUF];
        #pragma unroll
        for (int r = 0; r < ROWG; r++) {
            float zv = __shfl(zpart, r << 3, 64);
            acc0 += bp[r * G_ + lane] * zv;
            acc1 += bp[r * G_ + lane + 64] * zv;
            if (g2) acc2 += bp[r * G_ + lane + 128] * zv;
        }
    }
    accw[w * 176 + lane]      = acc0;
    accw[w * 176 + lane + 64] = acc1;
    if (g2) accw[w * 176 + lane + 128] = acc2;
    __syncthreads();

    // ======================= finalize for batch b =========================
    int k = *kptr; if (k > G_) k = G_;

    if (t < G_) {
        float s = 0.f;
        #pragma unroll
        for (int ww = 0; ww < NW; ww++) s += accw[ww * 176 + t];
        simall[t] = s;
        const float* bp = boxes + (size_t)(b * G_ + t) * AN * CH;
        float o = 0.f;
        for (int a = 0; a < AN; a++) o += bp[a * CH + 4];
        ms[t] = o / (float)AN;
    }
    // bb = b_vs . y
    {
        float part = b_vs[t] * ys[t];
        #pragma unroll
        for (int off = 32; off > 0; off >>= 1) part += __shfl_down(part, off);
        if (lane == 0) redw[w] = part;
    }
    __syncthreads();
    if (t == 0) {
        float s = 0.f;
        #pragma unroll
        for (int ww = 0; ww < NW; ww++) s += redw[ww];
        bbs = s;
    }

    // exact top-k via rank (value desc, index asc) -- matches lax.top_k ties
    if (t < G_) {
        float mv = ms[t];
        int rank = 0;
        for (int g = 0; g < G_; g++) {
            float o = ms[g];
            rank += (int)((o > mv) | ((o == mv) & (g < t)));
        }
        if (rank < k) selg[rank] = t;
    }
    __syncthreads();

    if (t < k) simv[t] = simall[selg[t]];
    __syncthreads();

    if (t == 0) {
        float best = -FLT_MAX; int br = 0;
        for (int r = 0; r < k; r++) if (simv[r] > best) { best = simv[r]; br = r; }
        int gs = selg[br];
        const float* bp = boxes + (size_t)(b * G_ + gs) * AN * CH;
        float bo = -FLT_MAX; int ai = 0;
        for (int a = 0; a < AN; a++) { float o = bp[a * CH + 4]; if (o > bo) { bo = o; ai = a; } }
        float cx = bp[ai * CH + 0], cy = bp[ai * CH + 1];
        float ww = bp[ai * CH + 2], hh = bp[ai * CH + 3];
        float x1 = cx - ww * 0.5f, y1 = cy - hh * 0.5f;
        out_box[(size_t)b * CH + 0] = x1;
        out_box[(size_t)b * CH + 1] = y1;
        out_box[(size_t)b * CH + 2] = x1 + ww;
        out_box[(size_t)b * CH + 3] = y1 + hh;
        for (int c = 4; c < CH; c++) out_box[(size_t)b * CH + c] = bp[ai * CH + c];
        out_max[b] = best + bbs;
        selp[0] = gs; selp[1] = ai;
    }
    __syncthreads();
    if (t < CM) {
        out_mask[(size_t)b * CM + t] =
            masks[((size_t)(b * G_ + selp[0]) * AN + selp[1]) * CM + t];
    }
}

extern "C" void kernel_launch(void* const* d_in, const int* in_sizes, int n_in,
                              void* d_out, int out_size, void* d_ws, size_t ws_size,
                              hipStream_t stream)
{
    const float* boxes = (const float*)d_in[0];
    const float* masks = (const float*)d_in[1];
    const float* feat  = (const float*)d_in[2];
    const float* lang  = (const float*)d_in[3];
    const float* W_vs  = (const float*)d_in[4];
    const float* b_vs  = (const float*)d_in[5];
    const float* W_ts  = (const float*)d_in[6];
    const float* b_ts  = (const float*)d_in[7];
    const int*   kptr  = (const int*)d_in[8];

    int H  = in_sizes[5];                  // 512
    int bs = in_sizes[3] / H;              // 256
    int AN = 3;
    int CH = in_sizes[0] / (bs * G_ * AN); // 5
    int CM = in_sizes[1] / (bs * G_ * AN); // 32

    float* py = (float*)d_ws;              // SPL*bs*H

    float* out_box  = (float*)d_out;
    float* out_mask = out_box + (size_t)bs * CH;
    float* out_max  = out_mask + (size_t)bs * CM;

    // py = split-K partials of lang @ W_ts
    dim3 g1(H / GBN, bs / GBM, SPL);
    gemm_splitk<<<g1, 256, 0, stream>>>(lang, W_ts, py, bs, H, H);
    // y + in-wave z (W-pipelined) + feat stream + finalize, one block per batch
    feat_final<<<bs, 512, 0, stream>>>(feat, py, W_vs, boxes, masks, b_ts, b_vs,
                                       kptr, out_box, out_mask, out_max,
                                       bs, AN, CH, CM);
}

// Round 15
// 56.270 us; speedup vs baseline: 2.3614x; 2.3614x over previous
//
#include <hip/hip_runtime.h>
#include <cfloat>
#include <cstdint>

#define GBM 64
#define GBN 64
#define GBK 64
#define GPAD 68     // 68*4=272B rows: 16B-aligned for b128 frags

#define G_    169
#define D_    1024
#define H_    512
#define NW    8     // waves per feat_final block
#define ROWG  8     // rows per staged feat group
#define NGRP  16    // groups per wave (128 rows)
#define GRPF  1352  // ROWG*G_ floats per group
#define NV    338   // GRPF/4 float4 per group
#define NBUF  3
#define SPL   8     // split-K slices

typedef unsigned int u32;

#define SB0 __builtin_amdgcn_sched_barrier(0)

__device__ __forceinline__ void gload_lds16(const float* g, float* l) {
    __builtin_amdgcn_global_load_lds(
        (const __attribute__((address_space(1))) u32*)g,
        (__attribute__((address_space(3))) u32*)l, 16, 0, 0);
}

// stage one 8x169 group: 6 gload_lds16 per wave (j=5 masked; still 6 vmcnt)
__device__ __forceinline__ void stage_group(const float* gsrc, float* ldsbase, int lane) {
    #pragma unroll
    for (int j = 0; j < 6; j++) {
        int idx = j * 64 + lane;
        if (idx < NV)
            gload_lds16(gsrc + 4 * idx, ldsbase + j * 256);
    }
}

// ---- split-K GEMM: py[s][M][N] partial of A[M,K] @ B[K,N], one 64^3 tile/block
__global__ __launch_bounds__(256) void gemm_splitk(
    const float* __restrict__ A, const float* __restrict__ B,
    float* __restrict__ Cpart, int M, int N, int K)
{
    __shared__ __align__(16) float Asm[GBK][GPAD];
    __shared__ __align__(16) float Bsm[GBK][GPAD];
    int t  = threadIdx.x;
    int m0 = blockIdx.y * GBM, n0 = blockIdx.x * GBN;
    int ks = blockIdx.z * GBK;

    #pragma unroll
    for (int i = 0; i < 4; i++) {
        int v = t + 256 * i;
        int m = v >> 4, k4 = (v & 15) * 4;
        float4 x = *(const float4*)&A[(size_t)(m0 + m) * K + ks + k4];
        Asm[k4 + 0][m] = x.x; Asm[k4 + 1][m] = x.y;
        Asm[k4 + 2][m] = x.z; Asm[k4 + 3][m] = x.w;
    }
    #pragma unroll
    for (int i = 0; i < 4; i++) {
        int v = t + 256 * i;
        int r = v >> 4, c4 = (v & 15) * 4;
        *(float4*)&Bsm[r][c4] = *(const float4*)&B[(size_t)(ks + r) * N + n0 + c4];
    }
    __syncthreads();

    int r4 = (t >> 4) * 4, c4 = (t & 15) * 4;
    float acc[4][4] = {{0.f}};
    #pragma unroll
    for (int kk = 0; kk < GBK; kk++) {
        float4 a = *(const float4*)&Asm[kk][r4];
        float4 b = *(const float4*)&Bsm[kk][c4];
        float av[4] = {a.x, a.y, a.z, a.w};
        float bv[4] = {b.x, b.y, b.z, b.w};
        #pragma unroll
        for (int i = 0; i < 4; i++)
            #pragma unroll
            for (int j = 0; j < 4; j++) acc[i][j] += av[i] * bv[j];
    }
    float* Cp = Cpart + (size_t)blockIdx.z * M * N;
    #pragma unroll
    for (int i = 0; i < 4; i++) {
        float4 v = {acc[i][0], acc[i][1], acc[i][2], acc[i][3]};
        *(float4*)&Cp[(size_t)(m0 + r4 + i) * N + n0 + c4] = v;
    }
}

// ---- feat_final: y from py; z per-wave via 4-row W sub-chunks (wrA/wrB, 64
// VGPR total) pipelined so 2 feat groups stay in flight (vmcnt(14) steady). --
__global__ __launch_bounds__(512) void feat_final(
    const float* __restrict__ feat, const float* __restrict__ py,
    const float* __restrict__ W_vs,
    const float* __restrict__ boxes, const float* __restrict__ masks,
    const float* __restrict__ b_ts, const float* __restrict__ b_vs,
    const int* __restrict__ kptr,
    float* __restrict__ out_box, float* __restrict__ out_mask,
    float* __restrict__ out_max,
    int bs, int AN, int CH, int CM)
{
    __shared__ __align__(16) float buf[NW][NBUF][GRPF];   // ~127 KB
    __shared__ __align__(16) float ys[H_];
    __shared__ float accw[NW * 176];
    __shared__ float simall[176];
    __shared__ float ms[176];
    __shared__ int   selg[176];
    __shared__ float simv[176];
    __shared__ float redw[NW];
    __shared__ float bbs;
    __shared__ int   selp[2];

    const int b = blockIdx.x;
    const int t = threadIdx.x;
    const int w = t >> 6, lane = t & 63;

    // ---- y = sum_s py[s][b] + b_ts ----
    {
        float yv = b_ts[t];
        #pragma unroll
        for (int s = 0; s < SPL; s++) yv += py[((size_t)s * bs + b) * H_ + t];
        ys[t] = yv;
    }
    __syncthreads();

    // W sub-chunk mapping: 4 rows, 16 lanes/row; lane covers cols cs4+jj*64
    const int cs4  = (lane & 15) * 4;
    const int row4 = lane >> 4;            // 0..3
    const float* Wbase = W_vs + ((size_t)(w * 128 + row4)) * H_ + cs4;
    const float* gsrc  = feat + ((size_t)b * D_ + (size_t)w * 128) * G_;

    float4 wrA[8], wrB[8];
    // prologue queue: [g0][SCa(0)][SCb(1)][g1]
    stage_group(gsrc, buf[w][0], lane);                         SB0;
    #pragma unroll
    for (int jj = 0; jj < 8; jj++)
        wrA[jj] = *(const float4*)&Wbase[(size_t)0 * 2048 + jj * 64];  SB0;
    #pragma unroll
    for (int jj = 0; jj < 8; jj++)
        wrB[jj] = *(const float4*)&Wbase[(size_t)1 * 2048 + jj * 64];  SB0;
    stage_group(gsrc + GRPF, buf[w][1], lane);                  SB0;

    float acc0 = 0.f, acc1 = 0.f, acc2 = 0.f;
    const bool g2 = lane < (G_ - 128);     // 41 lanes
    for (int gi = 0; gi < NGRP; gi++) {
        // wait1: retire SCa(2gi) (+ g(gi)); keep SCb+g(gi+1) [+newer]
        if (gi < NGRP - 1) asm volatile("s_waitcnt vmcnt(14)" ::: "memory");
        else               asm volatile("s_waitcnt vmcnt(8)"  ::: "memory");
        SB0;
        float zA = 0.f;
        #pragma unroll
        for (int jj = 0; jj < 8; jj++) {
            float4 yv = *(const float4*)&ys[cs4 + jj * 64];
            zA += wrA[jj].x * yv.x + wrA[jj].y * yv.y
                + wrA[jj].z * yv.z + wrA[jj].w * yv.w;
        }
        zA += __shfl_xor(zA, 1); zA += __shfl_xor(zA, 2);
        zA += __shfl_xor(zA, 4); zA += __shfl_xor(zA, 8);
        if (gi + 1 < NGRP) {               // SCa(2gi+2) -> wrA
            const float* Wp = Wbase + (size_t)(2 * gi + 2) * 2048;
            #pragma unroll
            for (int jj = 0; jj < 8; jj++)
                wrA[jj] = *(const float4*)&Wp[jj * 64];
        }
        SB0;
        // wait3: retire SCb(2gi+1); keep g(gi+1)+SCa' in flight
        if (gi < NGRP - 1) asm volatile("s_waitcnt vmcnt(14)" ::: "memory");
        else               asm volatile("s_waitcnt vmcnt(0)"  ::: "memory");
        SB0;
        float zB = 0.f;
        #pragma unroll
        for (int jj = 0; jj < 8; jj++) {
            float4 yv = *(const float4*)&ys[cs4 + jj * 64];
            zB += wrB[jj].x * yv.x + wrB[jj].y * yv.y
                + wrB[jj].z * yv.z + wrB[jj].w * yv.w;
        }
        zB += __shfl_xor(zB, 1); zB += __shfl_xor(zB, 2);
        zB += __shfl_xor(zB, 4); zB += __shfl_xor(zB, 8);
        if (gi + 1 < NGRP) {               // SCb(2gi+3) -> wrB
            const float* Wp = Wbase + (size_t)(2 * gi + 3) * 2048;
            #pragma unroll
            for (int jj = 0; jj < 8; jj++)
                wrB[jj] = *(const float4*)&Wp[jj * 64];
        }
        SB0;
        if (gi + 2 < NGRP)
            stage_group(gsrc + (size_t)(gi + 2) * GRPF, buf[w][(gi + 2) % NBUF], lane);
        SB0;
        // feat MACs for group gi: rows 0-3 use zA, rows 4-7 use zB
        const float* bp = buf[w][gi % NBUF];
        #pragma unroll
        for (int r = 0; r < 4; r++) {
            float zv = __shfl(zA, r << 4, 64);
            acc0 += bp[r * G_ + lane] * zv;
            acc1 += bp[r * G_ + lane + 64] * zv;
            if (g2) acc2 += bp[r * G_ + lane + 128] * zv;
        }
        #pragma unroll
        for (int r = 0; r < 4; r++) {
            float zv = __shfl(zB, r << 4, 64);
            acc0 += bp[(r + 4) * G_ + lane] * zv;
            acc1 += bp[(r + 4) * G_ + lane + 64] * zv;
            if (g2) acc2 += bp[(r + 4) * G_ + lane + 128] * zv;
        }
    }
    accw[w * 176 + lane]      = acc0;
    accw[w * 176 + lane + 64] = acc1;
    if (g2) accw[w * 176 + lane + 128] = acc2;
    __syncthreads();

    // ======================= finalize for batch b =========================
    int k = *kptr; if (k > G_) k = G_;

    if (t < G_) {
        float s = 0.f;
        #pragma unroll
        for (int ww = 0; ww < NW; ww++) s += accw[ww * 176 + t];
        simall[t] = s;
        const float* bp = boxes + (size_t)(b * G_ + t) * AN * CH;
        float o = 0.f;
        for (int a = 0; a < AN; a++) o += bp[a * CH + 4];
        ms[t] = o / (float)AN;
    }
    // bb = b_vs . y
    {
        float part = b_vs[t] * ys[t];
        #pragma unroll
        for (int off = 32; off > 0; off >>= 1) part += __shfl_down(part, off);
        if (lane == 0) redw[w] = part;
    }
    __syncthreads();
    if (t == 0) {
        float s = 0.f;
        #pragma unroll
        for (int ww = 0; ww < NW; ww++) s += redw[ww];
        bbs = s;
    }

    // exact top-k via rank (value desc, index asc) -- matches lax.top_k ties
    if (t < G_) {
        float mv = ms[t];
        int rank = 0;
        for (int g = 0; g < G_; g++) {
            float o = ms[g];
            rank += (int)((o > mv) | ((o == mv) & (g < t)));
        }
        if (rank < k) selg[rank] = t;
    }
    __syncthreads();

    if (t < k) simv[t] = simall[selg[t]];
    __syncthreads();

    if (t == 0) {
        float best = -FLT_MAX; int br = 0;
        for (int r = 0; r < k; r++) if (simv[r] > best) { best = simv[r]; br = r; }
        int gs = selg[br];
        const float* bp = boxes + (size_t)(b * G_ + gs) * AN * CH;
        float bo = -FLT_MAX; int ai = 0;
        for (int a = 0; a < AN; a++) { float o = bp[a * CH + 4]; if (o > bo) { bo = o; ai = a; } }
        float cx = bp[ai * CH + 0], cy = bp[ai * CH + 1];
        float ww = bp[ai * CH + 2], hh = bp[ai * CH + 3];
        float x1 = cx - ww * 0.5f, y1 = cy - hh * 0.5f;
        out_box[(size_t)b * CH + 0] = x1;
        out_box[(size_t)b * CH + 1] = y1;
        out_box[(size_t)b * CH + 2] = x1 + ww;
        out_box[(size_t)b * CH + 3] = y1 + hh;
        for (int c = 4; c < CH; c++) out_box[(size_t)b * CH + c] = bp[ai * CH + c];
        out_max[b] = best + bbs;
        selp[0] = gs; selp[1] = ai;
    }
    __syncthreads();
    if (t < CM) {
        out_mask[(size_t)b * CM + t] =
            masks[((size_t)(b * G_ + selp[0]) * AN + selp[1]) * CM + t];
    }
}

extern "C" void kernel_launch(void* const* d_in, const int* in_sizes, int n_in,
                              void* d_out, int out_size, void* d_ws, size_t ws_size,
                              hipStream_t stream)
{
    const float* boxes = (const float*)d_in[0];
    const float* masks = (const float*)d_in[1];
    const float* feat  = (const float*)d_in[2];
    const float* lang  = (const float*)d_in[3];
    const float* W_vs  = (const float*)d_in[4];
    const float* b_vs  = (const float*)d_in[5];
    const float* W_ts  = (const float*)d_in[6];
    const float* b_ts  = (const float*)d_in[7];
    const int*   kptr  = (const int*)d_in[8];

    int H  = in_sizes[5];                  // 512
    int bs = in_sizes[3] / H;              // 256
    int AN = 3;
    int CH = in_sizes[0] / (bs * G_ * AN); // 5
    int CM = in_sizes[1] / (bs * G_ * AN); // 32

    float* py = (float*)d_ws;              // SPL*bs*H

    float* out_box  = (float*)d_out;
    float* out_mask = out_box + (size_t)bs * CH;
    float* out_max  = out_mask + (size_t)bs * CM;

    // py = split-K partials of lang @ W_ts
    dim3 g1(H / GBN, bs / GBM, SPL);
    gemm_splitk<<<g1, 256, 0, stream>>>(lang, W_ts, py, bs, H, H);
    // y + in-wave z (sub-chunked W pipeline) + feat stream + finalize
    feat_final<<<bs, 512, 0, stream>>>(feat, py, W_vs, boxes, masks, b_ts, b_vs,
                                       kptr, out_box, out_mask, out_max,
                                       bs, AN, CH, CM);
}